// Round 2
// baseline (1361.591 us; speedup 1.0000x reference)
//
#include <hip/hip_runtime.h>
#include <stdint.h>

#define M_DIM 8192
#define N_DIM 4096
#define K_DIM 4096

typedef __attribute__((ext_vector_type(8))) short short8;   // 8 bf16 = 4 VGPR (MFMA A/B frag)
typedef __attribute__((ext_vector_type(4))) float f32x4;    // MFMA C/D frag

// ---------- helpers ----------
__device__ __forceinline__ unsigned fkey(float f) {
  unsigned u = __float_as_uint(f);
  return (u & 0x80000000u) ? ~u : (u | 0x80000000u);
}
__device__ __forceinline__ float finv(unsigned k) {
  return __uint_as_float((k & 0x80000000u) ? (k ^ 0x80000000u) : ~k);
}
// stats slots: [0]=xmin [1]=~xmax [2]=wmin [3]=~wmax [4]=amin [5]=~amax
// all init to 0xFF via hipMemsetAsync; all updated with atomicMin
// (max stored as flipped key so memset-0xFF works for both directions).
__device__ __forceinline__ unsigned short bf16_rne(float f) {
  unsigned u = __float_as_uint(f);
  unsigned r = u + 0x7FFFu + ((u >> 16) & 1u);
  return (unsigned short)(r >> 16);
}
__device__ __forceinline__ void async16(const unsigned short* g, unsigned short* l) {
  __builtin_amdgcn_global_load_lds(
      (const __attribute__((address_space(1))) void*)g,
      (__attribute__((address_space(3))) void*)l, 16, 0, 0);
}

// ---------- 1. fused min/max over x and w ----------
__global__ void minmax_fused(const float* __restrict__ x, const float* __restrict__ w,
                             unsigned* __restrict__ stats) {
  const bool isX = blockIdx.x < 2048;
  const float4* v4 = isX ? (const float4*)x : (const float4*)w;
  const int n4 = isX ? (M_DIM * K_DIM / 4) : (N_DIM * K_DIM / 4);
  const int bid = isX ? blockIdx.x : (blockIdx.x - 2048);
  const int nb = isX ? 2048 : 1024;
  int i0 = bid * blockDim.x + threadIdx.x;
  int stride = nb * blockDim.x;
  float vmin = 3.4e38f, vmax = -3.4e38f;
  for (int i = i0; i < n4; i += stride) {
    float4 t = v4[i];
    vmin = fminf(vmin, fminf(fminf(t.x, t.y), fminf(t.z, t.w)));
    vmax = fmaxf(vmax, fmaxf(fmaxf(t.x, t.y), fmaxf(t.z, t.w)));
  }
  unsigned kmin = fkey(vmin), kmax = ~fkey(vmax);
  #pragma unroll
  for (int off = 32; off; off >>= 1) {
    unsigned t0 = __shfl_down(kmin, (unsigned)off, 64);
    unsigned t1 = __shfl_down(kmax, (unsigned)off, 64);
    kmin = kmin < t0 ? kmin : t0;
    kmax = kmax < t1 ? kmax : t1;
  }
  if ((threadIdx.x & 63) == 0) {
    int base = isX ? 0 : 2;
    atomicMin(&stats[base + 0], kmin);
    atomicMin(&stats[base + 1], kmax);
  }
}

// ---------- 2. fused quantize: x -> Aq ; w -> Bq, Br ----------
// Aq = bf16(q_x - xzp)       (integer, |.|<=255, exact in bf16)
// Bq = bf16(q_w - wzp)       (integer, exact)
// Br = bf16(w - ws*(q_w-wzp))  (quantization residual)
__global__ void quant_fused(const float* __restrict__ x, const float* __restrict__ w,
                            const unsigned* __restrict__ stats,
                            unsigned short* __restrict__ Aq,
                            unsigned short* __restrict__ Bq,
                            unsigned short* __restrict__ Br) {
  if (blockIdx.x < 2048) {
    const float xmin = finv(stats[0]), xmax = finv(~stats[1]);
    const float xs = (xmax - xmin) / 255.0f;
    const float xzp = rintf(0.0f - xmin / xs);
    const float4* x4 = (const float4*)x;
    ushort4* a4 = (ushort4*)Aq;
    const int n4 = M_DIM * K_DIM / 4;
    int i0 = blockIdx.x * blockDim.x + threadIdx.x;
    int stride = 2048 * blockDim.x;
    for (int i = i0; i < n4; i += stride) {
      float4 t = x4[i];
      ushort4 o;
      o.x = bf16_rne(fminf(fmaxf(rintf(t.x / xs + xzp), 0.f), 255.f) - xzp);
      o.y = bf16_rne(fminf(fmaxf(rintf(t.y / xs + xzp), 0.f), 255.f) - xzp);
      o.z = bf16_rne(fminf(fmaxf(rintf(t.z / xs + xzp), 0.f), 255.f) - xzp);
      o.w = bf16_rne(fminf(fmaxf(rintf(t.w / xs + xzp), 0.f), 255.f) - xzp);
      a4[i] = o;
    }
  } else {
    const float wmin = finv(stats[2]), wmax = finv(~stats[3]);
    const float ws = (wmax - wmin) / 255.0f;
    const float wzp = rintf(-128.0f - wmin / ws);
    const float4* w4 = (const float4*)w;
    ushort4* q4 = (ushort4*)Bq;
    ushort4* r4 = (ushort4*)Br;
    const int n4 = N_DIM * K_DIM / 4;
    int i0 = (blockIdx.x - 2048) * blockDim.x + threadIdx.x;
    int stride = 1024 * blockDim.x;
    for (int i = i0; i < n4; i += stride) {
      float4 t = w4[i];
      ushort4 q, r;
      float v, qe;
      v = t.x; qe = fminf(fmaxf(rintf(v / ws + wzp), -128.f), 127.f) - wzp;
      q.x = bf16_rne(qe); r.x = bf16_rne(v - ws * qe);
      v = t.y; qe = fminf(fmaxf(rintf(v / ws + wzp), -128.f), 127.f) - wzp;
      q.y = bf16_rne(qe); r.y = bf16_rne(v - ws * qe);
      v = t.z; qe = fminf(fmaxf(rintf(v / ws + wzp), -128.f), 127.f) - wzp;
      q.z = bf16_rne(qe); r.z = bf16_rne(v - ws * qe);
      v = t.w; qe = fminf(fmaxf(rintf(v / ws + wzp), -128.f), 127.f) - wzp;
      q.w = bf16_rne(qe); r.w = bf16_rne(v - ws * qe);
      q4[i] = q; r4[i] = r;
    }
  }
}

// ---------- 3. fused GEMM: out_pre = xs*ws*(A@Bq^T) + bias (stored);
//                          act = out_pre + xs*(A@Br^T)  (min/max only) ----------
// 128x128 tile, BK=64, 4 waves (2x2) each 64x64. Fragment-order LDS layout:
// tile stored as 16 band-halves of 1KB; band-half (bb,h) holds the 16x32
// sub-tile rows bb*16..+15, k h*32..+31, in exact MFMA-fragment lane order
// (chunk L = row L&15, k-chunk L>>4). Staging gathers global so that
// global_load_lds's "base + lane*16" lands fragment-ordered; compute reads
// are band*1024 + lane*16 -> lane-sequential, zero bank conflicts.
__global__ __launch_bounds__(256, 2) void gemm_fused(
    const unsigned short* __restrict__ A,   // [8192][4096] bf16 (q_x - xzp)
    const unsigned short* __restrict__ Bq,  // [4096][4096] bf16 (q_w - wzp)
    const unsigned short* __restrict__ Br,  // [4096][4096] bf16 residual
    const float* __restrict__ bias,
    unsigned* __restrict__ stats,
    float* __restrict__ outp)               // [8192][4096] fp32 pre-requant
{
  __shared__ __align__(16) unsigned short sA[128 * 64];
  __shared__ __align__(16) unsigned short sBq[128 * 64];
  __shared__ __align__(16) unsigned short sBr[128 * 64];
  __shared__ unsigned s_red[2];

  const int tid = threadIdx.x;
  const int wave = tid >> 6;
  const int lane = tid & 63;
  const int bm = blockIdx.x >> 5;          // 64 row-blocks
  const int bn = blockIdx.x & 31;          // 32 col-blocks
  const int rowBase = bm * 128;
  const int colBase = bn * 128;
  const int wr = wave >> 1;
  const int wc = wave & 1;
  const int laneR = lane & 15;             // fragment row within band
  const int laneC8 = (lane >> 4) * 8;      // fragment k-chunk (elems)

  if (tid == 0) { s_red[0] = 0xFFFFFFFFu; s_red[1] = 0xFFFFFFFFu; }

  f32x4 acc_q[4][4];
  f32x4 acc_r[4][4];
  const f32x4 zero = {0.f, 0.f, 0.f, 0.f};
  #pragma unroll
  for (int i = 0; i < 4; ++i)
    #pragma unroll
    for (int j = 0; j < 4; ++j) { acc_q[i][j] = zero; acc_r[i][j] = zero; }

  // 48 staging units per K-iter: unit = mat*16 + bb*2 + h; this wave does
  // units j*4+wave. Pointers are loop-invariant except +kt.
  const unsigned short* srcs[12];
  unsigned short* dsts[12];
  #pragma unroll
  for (int j = 0; j < 12; ++j) {
    const int unit = j * 4 + wave;
    const int mat = unit >> 4;
    const int bb = (unit >> 1) & 7;
    const int h = unit & 1;
    const int rowG = (mat == 0 ? rowBase : colBase) + bb * 16 + laneR;
    const unsigned short* gbase = (mat == 0) ? A : (mat == 1 ? Bq : Br);
    unsigned short* lbase = (mat == 0) ? sA : (mat == 1 ? sBq : sBr);
    srcs[j] = gbase + (size_t)rowG * K_DIM + h * 32 + laneC8;
    dsts[j] = lbase + (bb * 2 + h) * 512 + lane * 8;
  }

  for (int kt = 0; kt < K_DIM; kt += 64) {
    #pragma unroll
    for (int j = 0; j < 12; ++j) async16(srcs[j] + kt, dsts[j]);
    __syncthreads();

    #pragma unroll
    for (int h = 0; h < 2; ++h) {
      short8 af[4];
      #pragma unroll
      for (int mi = 0; mi < 4; ++mi)
        af[mi] = *(const short8*)(sA + ((wr * 4 + mi) * 2 + h) * 512 + lane * 8);
      #pragma unroll
      for (int ni = 0; ni < 4; ++ni) {
        const int bo = ((wc * 4 + ni) * 2 + h) * 512 + lane * 8;
        short8 bq = *(const short8*)(sBq + bo);
        short8 br = *(const short8*)(sBr + bo);
        #pragma unroll
        for (int mi = 0; mi < 4; ++mi) {
          acc_q[mi][ni] = __builtin_amdgcn_mfma_f32_16x16x32_bf16(af[mi], bq, acc_q[mi][ni], 0, 0, 0);
          acc_r[mi][ni] = __builtin_amdgcn_mfma_f32_16x16x32_bf16(af[mi], br, acc_r[mi][ni], 0, 0, 0);
        }
      }
    }
    __syncthreads();
  }

  // epilogue: compute scales from stats, write out_pre, reduce act min/max
  const float xmin = finv(stats[0]), xmax = finv(~stats[1]);
  const float xs = (xmax - xmin) / 255.0f;
  const float wmin = finv(stats[2]), wmax = finv(~stats[3]);
  const float wsc = (wmax - wmin) / 255.0f;
  const float sw = xs * wsc;
  unsigned kmin = 0xFFFFFFFFu, kmax = 0xFFFFFFFFu;   // kmax holds flipped keys

  #pragma unroll
  for (int ni = 0; ni < 4; ++ni) {
    const int col = colBase + wc * 64 + ni * 16 + laneR;
    const float bv = bias[col];
    #pragma unroll
    for (int mi = 0; mi < 4; ++mi) {
      const int row0 = rowBase + wr * 64 + mi * 16 + (lane >> 4) * 4;
      #pragma unroll
      for (int r = 0; r < 4; ++r) {
        const float ov = sw * acc_q[mi][ni][r] + bv;          // out_pre
        const float av = ov + xs * acc_r[mi][ni][r];          // act
        const unsigned k = fkey(av);
        const unsigned kf = ~k;
        kmin = kmin < k ? kmin : k;
        kmax = kmax < kf ? kmax : kf;
        outp[(size_t)(row0 + r) * N_DIM + col] = ov;
      }
    }
  }

  #pragma unroll
  for (int off = 32; off; off >>= 1) {
    unsigned t0 = __shfl_down(kmin, (unsigned)off, 64);
    unsigned t1 = __shfl_down(kmax, (unsigned)off, 64);
    kmin = kmin < t0 ? kmin : t0;
    kmax = kmax < t1 ? kmax : t1;
  }
  __syncthreads();
  if (lane == 0) { atomicMin(&s_red[0], kmin); atomicMin(&s_red[1], kmax); }
  __syncthreads();
  if (tid == 0) { atomicMin(&stats[4], s_red[0]); atomicMin(&stats[5], s_red[1]); }
}

// ---------- 4. requantize out in place (computes a-params inline) ----------
__global__ void requant_kernel(float* __restrict__ out, const unsigned* __restrict__ stats, int n4) {
  const float amin = finv(stats[4]), amax = finv(~stats[5]);
  const float as = (amax - amin) / 255.0f;
  const float azp = rintf(0.0f - amin / as);
  float4* o4 = (float4*)out;
  int i0 = blockIdx.x * blockDim.x + threadIdx.x;
  int stride = gridDim.x * blockDim.x;
  for (int i = i0; i < n4; i += stride) {
    float4 t = o4[i];
    t.x = (fminf(fmaxf(rintf(t.x / as + azp), 0.f), 255.f) - azp) * as;
    t.y = (fminf(fmaxf(rintf(t.y / as + azp), 0.f), 255.f) - azp) * as;
    t.z = (fminf(fmaxf(rintf(t.z / as + azp), 0.f), 255.f) - azp) * as;
    t.w = (fminf(fmaxf(rintf(t.w / as + azp), 0.f), 255.f) - azp) * as;
    o4[i] = t;
  }
}

extern "C" void kernel_launch(void* const* d_in, const int* in_sizes, int n_in,
                              void* d_out, int out_size, void* d_ws, size_t ws_size,
                              hipStream_t stream) {
  const float* x = (const float*)d_in[0];      // [8192,4096]
  const float* w = (const float*)d_in[1];      // [4096,4096]
  const float* bias = (const float*)d_in[2];   // [4096]
  float* out = (float*)d_out;                  // [8192,4096]

  // workspace: stats(24B) | Aq 64MB | Bq 32MB | Br 32MB  (~128MB)
  unsigned* stats = (unsigned*)d_ws;
  unsigned short* Aq = (unsigned short*)((char*)d_ws + 256);
  unsigned short* Bq = Aq + (size_t)M_DIM * K_DIM;
  unsigned short* Br = Bq + (size_t)N_DIM * K_DIM;

  hipMemsetAsync(stats, 0xFF, 24, stream);
  minmax_fused<<<3072, 256, 0, stream>>>(x, w, stats);
  quant_fused<<<3072, 256, 0, stream>>>(x, w, stats, Aq, Bq, Br);
  gemm_fused<<<(M_DIM / 128) * (N_DIM / 128), 256, 0, stream>>>(Aq, Bq, Br, bias, stats, out);
  requant_kernel<<<2048, 256, 0, stream>>>(out, stats, M_DIM * N_DIM / 4);
}

// Round 3
// 992.241 us; speedup vs baseline: 1.3722x; 1.3722x over previous
//
#include <hip/hip_runtime.h>
#include <stdint.h>

#define M_DIM 8192
#define N_DIM 4096
#define K_DIM 4096

typedef __attribute__((ext_vector_type(4))) int i32x4;   // i8 MFMA A/B frag (16 i8) and C/D (4 i32)

// ---------- helpers ----------
__device__ __forceinline__ unsigned fkey(float f) {
  unsigned u = __float_as_uint(f);
  return (u & 0x80000000u) ? ~u : (u | 0x80000000u);
}
__device__ __forceinline__ float finv(unsigned k) {
  return __uint_as_float((k & 0x80000000u) ? (k ^ 0x80000000u) : ~k);
}
// stats slots (all atomicMin on fkey; max stored flipped): [0]xmin [1]~xmax [2]wmin [3]~wmax [4]amin [5]~amax
__device__ __forceinline__ void async16(const void* g, void* l) {
  __builtin_amdgcn_global_load_lds(
      (const __attribute__((address_space(1))) void*)g,
      (__attribute__((address_space(3))) void*)l, 16, 0, 0);
}

// ---------- 1. fused min/max over x and w ----------
__global__ void minmax_fused(const float* __restrict__ x, const float* __restrict__ w,
                             unsigned* __restrict__ stats) {
  const bool isX = blockIdx.x < 2048;
  const float4* v4 = isX ? (const float4*)x : (const float4*)w;
  const int n4 = isX ? (M_DIM * K_DIM / 4) : (N_DIM * K_DIM / 4);
  const int bid = isX ? blockIdx.x : (blockIdx.x - 2048);
  const int nb = isX ? 2048 : 1024;
  int i0 = bid * blockDim.x + threadIdx.x;
  int stride = nb * blockDim.x;
  float vmin = 3.4e38f, vmax = -3.4e38f;
  for (int i = i0; i < n4; i += stride) {
    float4 t = v4[i];
    vmin = fminf(vmin, fminf(fminf(t.x, t.y), fminf(t.z, t.w)));
    vmax = fmaxf(vmax, fmaxf(fmaxf(t.x, t.y), fmaxf(t.z, t.w)));
  }
  unsigned kmin = fkey(vmin), kmax = ~fkey(vmax);
  #pragma unroll
  for (int off = 32; off; off >>= 1) {
    unsigned t0 = __shfl_down(kmin, (unsigned)off, 64);
    unsigned t1 = __shfl_down(kmax, (unsigned)off, 64);
    kmin = kmin < t0 ? kmin : t0;
    kmax = kmax < t1 ? kmax : t1;
  }
  if ((threadIdx.x & 63) == 0) {
    int base = isX ? 0 : 2;
    atomicMin(&stats[base + 0], kmin);
    atomicMin(&stats[base + 1], kmax);
  }
}

// ---------- 2. fused quantize, row-per-block, emits row/col sums ----------
// blocks [0,8192): x row -> A8 = q_x - 128 (i8), rowA[m] = sum_k A8
// blocks [8192,12288): w row n -> B8 = q_w (i8), R8 = round(resid*126/ws),
//                      colB[n] = sum_k B8, colR[n] = sum_k R8
__global__ void quant_fused(const float* __restrict__ x, const float* __restrict__ w,
                            const unsigned* __restrict__ stats,
                            signed char* __restrict__ A8, signed char* __restrict__ B8,
                            signed char* __restrict__ R8,
                            int* __restrict__ rowA, int* __restrict__ colB, int* __restrict__ colR) {
  __shared__ int sr[8];
  const int tid = threadIdx.x;
  const int lane = tid & 63;
  const int wv = tid >> 6;
  if (blockIdx.x < M_DIM) {
    const int row = blockIdx.x;
    const float xmin = finv(stats[0]), xmax = finv(~stats[1]);
    const float xs = (xmax - xmin) / 255.0f;
    const float xzp = rintf(0.0f - xmin / xs);
    const float4* xr = (const float4*)(x + (size_t)row * K_DIM);
    char4* ar = (char4*)(A8 + (size_t)row * K_DIM);
    int s = 0;
    #pragma unroll
    for (int i = 0; i < 4; ++i) {
      int idx = tid + i * 256;
      float4 t = xr[idx];
      int q0 = (int)(fminf(fmaxf(rintf(t.x / xs + xzp), 0.f), 255.f)) - 128;
      int q1 = (int)(fminf(fmaxf(rintf(t.y / xs + xzp), 0.f), 255.f)) - 128;
      int q2 = (int)(fminf(fmaxf(rintf(t.z / xs + xzp), 0.f), 255.f)) - 128;
      int q3 = (int)(fminf(fmaxf(rintf(t.w / xs + xzp), 0.f), 255.f)) - 128;
      char4 c4; c4.x = (signed char)q0; c4.y = (signed char)q1;
      c4.z = (signed char)q2; c4.w = (signed char)q3;
      ar[idx] = c4;
      s += q0 + q1 + q2 + q3;
    }
    #pragma unroll
    for (int off = 32; off; off >>= 1) s += __shfl_down(s, (unsigned)off, 64);
    if (lane == 0) sr[wv] = s;
    __syncthreads();
    if (tid == 0) rowA[row] = sr[0] + sr[1] + sr[2] + sr[3];
  } else {
    const int row = blockIdx.x - M_DIM;            // w row n == B col n
    const float wmin = finv(stats[2]), wmax = finv(~stats[3]);
    const float ws = (wmax - wmin) / 255.0f;
    const float wzp = rintf(-128.0f - wmin / ws);
    const float inv_rs = 126.0f / ws;
    const float4* wr = (const float4*)(w + (size_t)row * K_DIM);
    char4* br = (char4*)(B8 + (size_t)row * K_DIM);
    char4* rr = (char4*)(R8 + (size_t)row * K_DIM);
    int sb = 0, srr = 0;
    #pragma unroll
    for (int i = 0; i < 4; ++i) {
      int idx = tid + i * 256;
      float4 t = wr[idx];
      char4 bq, rq;
      float v, qf; int q, r;
      v = t.x; qf = fminf(fmaxf(rintf(v / ws + wzp), -128.f), 127.f); q = (int)qf;
      r = (int)fminf(fmaxf(rintf((v - ws * (qf - wzp)) * inv_rs), -127.f), 127.f);
      bq.x = (signed char)q; rq.x = (signed char)r; sb += q; srr += r;
      v = t.y; qf = fminf(fmaxf(rintf(v / ws + wzp), -128.f), 127.f); q = (int)qf;
      r = (int)fminf(fmaxf(rintf((v - ws * (qf - wzp)) * inv_rs), -127.f), 127.f);
      bq.y = (signed char)q; rq.y = (signed char)r; sb += q; srr += r;
      v = t.z; qf = fminf(fmaxf(rintf(v / ws + wzp), -128.f), 127.f); q = (int)qf;
      r = (int)fminf(fmaxf(rintf((v - ws * (qf - wzp)) * inv_rs), -127.f), 127.f);
      bq.z = (signed char)q; rq.z = (signed char)r; sb += q; srr += r;
      v = t.w; qf = fminf(fmaxf(rintf(v / ws + wzp), -128.f), 127.f); q = (int)qf;
      r = (int)fminf(fmaxf(rintf((v - ws * (qf - wzp)) * inv_rs), -127.f), 127.f);
      bq.w = (signed char)q; rq.w = (signed char)r; sb += q; srr += r;
      br[idx] = bq; rr[idx] = rq;
    }
    #pragma unroll
    for (int off = 32; off; off >>= 1) {
      sb += __shfl_down(sb, (unsigned)off, 64);
      srr += __shfl_down(srr, (unsigned)off, 64);
    }
    if (lane == 0) { sr[wv] = sb; sr[4 + wv] = srr; }
    __syncthreads();
    if (tid == 0) {
      colB[row] = sr[0] + sr[1] + sr[2] + sr[3];
      colR[row] = sr[4] + sr[5] + sr[6] + sr[7];
    }
  }
}

// ---------- 3. int8 GEMM, dual chain ----------
// 128x128 tile, BK=64, 8 waves (2x4), each wave 64m x 32n.
// Fragment-order LDS: band bb (16 rows x 64 K = 1KB); lane L holds
// row bb*16+(L&15), k-bytes (L>>4)*16..+15 -> glds "base+16L" lands exact.
// mfma_i32_16x16x64_i8: A[m=L&15][k=(L>>4)*16+j]; C/D col=L&15, row=(L>>4)*4+reg.
__global__ __launch_bounds__(512, 4) void gemm_i8(
    const signed char* __restrict__ A8, const signed char* __restrict__ B8,
    const signed char* __restrict__ R8,
    const int* __restrict__ rowA, const int* __restrict__ colB, const int* __restrict__ colR,
    const float* __restrict__ bias, unsigned* __restrict__ stats,
    float* __restrict__ outp) {
  __shared__ __align__(16) signed char sA[128 * 64];
  __shared__ __align__(16) signed char sB[128 * 64];
  __shared__ __align__(16) signed char sR[128 * 64];
  __shared__ unsigned s_red[2];

  const int tid = threadIdx.x;
  const int wave = tid >> 6;               // 0..7
  const int lane = tid & 63;
  // XCD-swizzle: blocks of one XCD cover 4 bn x 64 bm -> B-tile (1MB) L2-resident
  const int xcd = blockIdx.x & 7;
  const int s = blockIdx.x >> 3;           // 0..255
  const int bn = xcd * 4 + (s >> 6);
  const int bm = s & 63;
  const int rowBase = bm * 128;
  const int colBase = bn * 128;
  const int wr = wave >> 2;                // 0..1 (m half)
  const int wc = wave & 3;                 // 0..3 (n quarter)
  const int laneR = lane & 15;
  const int laneK = (lane >> 4) * 16;

  if (tid == 0) { s_red[0] = 0xFFFFFFFFu; s_red[1] = 0xFFFFFFFFu; }

  i32x4 acc_q[4][2];
  i32x4 acc_r[4][2];
  const i32x4 zero = {0, 0, 0, 0};
  #pragma unroll
  for (int i = 0; i < 4; ++i) { acc_q[i][0] = zero; acc_q[i][1] = zero;
                                acc_r[i][0] = zero; acc_r[i][1] = zero; }

  // each wave stages band bb=wave of each matrix (1KB each)
  const signed char* srcA = A8 + (size_t)(rowBase + wave * 16 + laneR) * K_DIM + laneK;
  const signed char* srcB = B8 + (size_t)(colBase + wave * 16 + laneR) * K_DIM + laneK;
  const signed char* srcR = R8 + (size_t)(colBase + wave * 16 + laneR) * K_DIM + laneK;
  signed char* dA = sA + wave * 1024 + lane * 16;
  signed char* dB = sB + wave * 1024 + lane * 16;
  signed char* dR = sR + wave * 1024 + lane * 16;

  for (int kt = 0; kt < K_DIM; kt += 64) {
    async16(srcA + kt, dA);
    async16(srcB + kt, dB);
    async16(srcR + kt, dR);
    __syncthreads();

    i32x4 af[4];
    #pragma unroll
    for (int mi = 0; mi < 4; ++mi)
      af[mi] = *(const i32x4*)(sA + (wr * 4 + mi) * 1024 + lane * 16);
    #pragma unroll
    for (int ni = 0; ni < 2; ++ni) {
      const int bo = (wc * 2 + ni) * 1024 + lane * 16;
      i32x4 bf = *(const i32x4*)(sB + bo);
      i32x4 rf = *(const i32x4*)(sR + bo);
      #pragma unroll
      for (int mi = 0; mi < 4; ++mi) {
        acc_q[mi][ni] = __builtin_amdgcn_mfma_i32_16x16x64_i8(af[mi], bf, acc_q[mi][ni], 0, 0, 0);
        acc_r[mi][ni] = __builtin_amdgcn_mfma_i32_16x16x64_i8(af[mi], rf, acc_r[mi][ni], 0, 0, 0);
      }
    }
    __syncthreads();
  }

  // epilogue: integer corrections (exact), write out_pre, reduce act min/max
  const float xmin = finv(stats[0]), xmax = finv(~stats[1]);
  const float xs = (xmax - xmin) / 255.0f;
  const float xzp = rintf(0.0f - xmin / xs);
  const float wmin = finv(stats[2]), wmax = finv(~stats[3]);
  const float ws = (wmax - wmin) / 255.0f;
  const float wzp = rintf(-128.0f - wmin / ws);
  const int c = 128 - (int)xzp;
  const int wzpi = (int)wzp;
  const float sw = xs * ws;
  const float xrs = xs * (ws / 126.0f);
  const int ccK = c * wzpi * K_DIM;
  unsigned kmin = 0xFFFFFFFFu, kmax = 0xFFFFFFFFu;

  int rAv[4][4];
  #pragma unroll
  for (int mi = 0; mi < 4; ++mi) {
    const int row0 = rowBase + wr * 64 + mi * 16 + (lane >> 4) * 4;
    #pragma unroll
    for (int r = 0; r < 4; ++r) rAv[mi][r] = rowA[row0 + r];
  }

  #pragma unroll
  for (int ni = 0; ni < 2; ++ni) {
    const int col = colBase + wc * 32 + ni * 16 + laneR;
    const float bv = bias[col];
    const int base_n = c * colB[col] - ccK;
    const int cR = c * colR[col];
    #pragma unroll
    for (int mi = 0; mi < 4; ++mi) {
      const int row0 = rowBase + wr * 64 + mi * 16 + (lane >> 4) * 4;
      #pragma unroll
      for (int r = 0; r < 4; ++r) {
        const int S = acc_q[mi][ni][r] + base_n - wzpi * rAv[mi][r];
        const float ov = sw * (float)S + bv;
        const int S2 = acc_r[mi][ni][r] + cR;
        const float av = ov + xrs * (float)S2;
        const unsigned k = fkey(av);
        const unsigned kf = ~k;
        kmin = kmin < k ? kmin : k;
        kmax = kmax < kf ? kmax : kf;
        outp[(size_t)(row0 + r) * N_DIM + col] = ov;
      }
    }
  }

  #pragma unroll
  for (int off = 32; off; off >>= 1) {
    unsigned t0 = __shfl_down(kmin, (unsigned)off, 64);
    unsigned t1 = __shfl_down(kmax, (unsigned)off, 64);
    kmin = kmin < t0 ? kmin : t0;
    kmax = kmax < t1 ? kmax : t1;
  }
  __syncthreads();
  if (lane == 0) { atomicMin(&s_red[0], kmin); atomicMin(&s_red[1], kmax); }
  __syncthreads();
  if (tid == 0) { atomicMin(&stats[4], s_red[0]); atomicMin(&stats[5], s_red[1]); }
}

// ---------- 4. requantize out in place ----------
__global__ void requant_kernel(float* __restrict__ out, const unsigned* __restrict__ stats, int n4) {
  const float amin = finv(stats[4]), amax = finv(~stats[5]);
  const float as = (amax - amin) / 255.0f;
  const float azp = rintf(0.0f - amin / as);
  float4* o4 = (float4*)out;
  int i0 = blockIdx.x * blockDim.x + threadIdx.x;
  int stride = gridDim.x * blockDim.x;
  for (int i = i0; i < n4; i += stride) {
    float4 t = o4[i];
    t.x = (fminf(fmaxf(rintf(t.x / as + azp), 0.f), 255.f) - azp) * as;
    t.y = (fminf(fmaxf(rintf(t.y / as + azp), 0.f), 255.f) - azp) * as;
    t.z = (fminf(fmaxf(rintf(t.z / as + azp), 0.f), 255.f) - azp) * as;
    t.w = (fminf(fmaxf(rintf(t.w / as + azp), 0.f), 255.f) - azp) * as;
    o4[i] = t;
  }
}

extern "C" void kernel_launch(void* const* d_in, const int* in_sizes, int n_in,
                              void* d_out, int out_size, void* d_ws, size_t ws_size,
                              hipStream_t stream) {
  const float* x = (const float*)d_in[0];      // [8192,4096]
  const float* w = (const float*)d_in[1];      // [4096,4096]
  const float* bias = (const float*)d_in[2];   // [4096]
  float* out = (float*)d_out;                  // [8192,4096]

  // workspace: stats | A8 32MB | B8 16MB | R8 16MB | rowA | colB | colR  (~64.1MB)
  unsigned* stats = (unsigned*)d_ws;
  signed char* A8 = (signed char*)d_ws + 256;
  signed char* B8 = A8 + (size_t)M_DIM * K_DIM;
  signed char* R8 = B8 + (size_t)N_DIM * K_DIM;
  int* rowA = (int*)(R8 + (size_t)N_DIM * K_DIM);
  int* colB = rowA + M_DIM;
  int* colR = colB + N_DIM;

  hipMemsetAsync(stats, 0xFF, 24, stream);
  minmax_fused<<<3072, 256, 0, stream>>>(x, w, stats);
  quant_fused<<<M_DIM + N_DIM, 256, 0, stream>>>(x, w, stats, A8, B8, R8, rowA, colB, colR);
  gemm_i8<<<(M_DIM / 128) * (N_DIM / 128), 512, 0, stream>>>(A8, B8, R8, rowA, colB, colR, bias, stats, out);
  requant_kernel<<<2048, 256, 0, stream>>>(out, stats, M_DIM * N_DIM / 4);
}